// Round 1
// baseline (3669.998 us; speedup 1.0000x reference)
//
#include <hip/hip_runtime.h>
#include <math.h>

#define BATCH 8
#define SEQ   2048      // LQ == LK
#define DIM   1024      // DQ == DK == DV
#define TOPK  64
#define NEGMASK -1e30f

#define PAD_A 68
#define PAD_B 132

// ---------------- colsum of values over t, per (b, d) ----------------
// two-stage deterministic reduction: partial[tc][b][d] then reduce.
__global__ __launch_bounds__(256) void colsum_partial_kernel(
    const float* __restrict__ values, float* __restrict__ partial) {
  int bid = blockIdx.x;          // 256 = tc(8) * b(8) * dg(4)
  int tc = bid >> 5;
  int b  = (bid >> 2) & 7;
  int dg = bid & 3;
  int d  = dg * 256 + threadIdx.x;
  const float* vp = values + ((size_t)b * SEQ + (size_t)tc * 256) * DIM + d;
  float s = 0.f;
  #pragma unroll 8
  for (int t = 0; t < 256; ++t) s += vp[(size_t)t * DIM];
  partial[((size_t)tc * BATCH + b) * DIM + d] = s;
}

__global__ __launch_bounds__(256) void colsum_reduce_kernel(
    const float* __restrict__ partial, float* __restrict__ colsum) {
  int idx = blockIdx.x * 256 + threadIdx.x;   // 8192 = 8*1024
  int b = idx >> 10, d = idx & 1023;
  float s = 0.f;
  #pragma unroll
  for (int tc = 0; tc < 8; ++tc) s += partial[((size_t)tc * BATCH + b) * DIM + d];
  colsum[idx] = s;
}

// ---------------- q_proj = Q @ W^T  (both row-major, K contiguous) ----------------
// C[16384][1024]; tiles 64x64, BK=32, 256 threads, 4x4 per thread.
__global__ __launch_bounds__(256) void qproj_kernel(
    const float* __restrict__ Q, const float* __restrict__ W,
    float* __restrict__ C) {
  __shared__ float As[32][PAD_A];   // [k][m], padded so b128 reads stay aligned + banks rotate
  __shared__ float Bs[32][PAD_A];   // [k][n]
  const int m0 = blockIdx.x * 64;
  const int n0 = blockIdx.y * 64;
  const int tid = threadIdx.x;
  const int tx = tid & 15, ty = tid >> 4;
  const int lrow = tid >> 3;          // 0..31
  const int lk   = (tid & 7) * 4;     // 0..28
  float acc[4][4];
  #pragma unroll
  for (int i = 0; i < 4; ++i)
    #pragma unroll
    for (int j = 0; j < 4; ++j) acc[i][j] = 0.f;

  for (int k0 = 0; k0 < DIM; k0 += 32) {
    #pragma unroll
    for (int it = 0; it < 2; ++it) {
      int r = lrow + it * 32;
      float4 a = *(const float4*)(Q + (size_t)(m0 + r) * DIM + k0 + lk);
      As[lk + 0][r] = a.x; As[lk + 1][r] = a.y; As[lk + 2][r] = a.z; As[lk + 3][r] = a.w;
      float4 w = *(const float4*)(W + (size_t)(n0 + r) * DIM + k0 + lk);
      Bs[lk + 0][r] = w.x; Bs[lk + 1][r] = w.y; Bs[lk + 2][r] = w.z; Bs[lk + 3][r] = w.w;
    }
    __syncthreads();
    #pragma unroll
    for (int k = 0; k < 32; ++k) {
      float4 av = *(const float4*)&As[k][ty * 4];
      float4 bv = *(const float4*)&Bs[k][tx * 4];
      float ar[4] = {av.x, av.y, av.z, av.w};
      float br[4] = {bv.x, bv.y, bv.z, bv.w};
      #pragma unroll
      for (int i = 0; i < 4; ++i)
        #pragma unroll
        for (int j = 0; j < 4; ++j)
          acc[i][j] = fmaf(ar[i], br[j], acc[i][j]);
    }
    __syncthreads();
  }
  #pragma unroll
  for (int i = 0; i < 4; ++i) {
    float4 o = {acc[i][0], acc[i][1], acc[i][2], acc[i][3]};
    *(float4*)(C + (size_t)(m0 + ty * 4 + i) * DIM + n0 + tx * 4) = o;
  }
}

// ---------------- scores GEMM + mask + softmax stats + topk + gather epilogue ----------------
// One block: 64 q-rows, 512 threads (8 waves). Phase 1: scores tile-GEMM -> ws.
// Phase 2: per wave, 8 rows: max, Z, descending top-64 extract (early stop), gather V.
union ScoresSM {
  struct { float A[32][PAD_A]; float Bt[32][PAD_B]; } p1;  // ~25.6 KB
  float rows[8][2048];                                     // 64 KB
};

__global__ __launch_bounds__(512) void scores_kernel(
    const float* __restrict__ qproj,    // [16384][1024]
    const float* __restrict__ keys,     // [8][2048][1024]
    const float* __restrict__ values,   // [8][2048][1024]
    const int*   __restrict__ mask,     // [8][2048][2048]
    const float* __restrict__ colsum,   // [8][1024]
    float* __restrict__ scores_ws,      // [16384][2048]
    float* __restrict__ out)            // [16384][1024]
{
  __shared__ ScoresSM sm;
  const int blk  = blockIdx.x;       // 0..255
  const int b    = blk >> 5;
  const int row0 = blk * 64;         // global flat q-row = b*2048 + qt*64
  const int tid  = threadIdx.x;
  const int tx = tid & 31, ty = tid >> 5;   // tx: 128 cols /4 ; ty: 64 rows /4
  const int lrow = tid >> 3;                // 0..63
  const int lk   = (tid & 7) * 4;
  const float* keysb = keys + (size_t)b * SEQ * DIM;

  // ---- phase 1: scores[64][2048] in tiles of 64x128, K=1024, BK=32 ----
  for (int t0 = 0; t0 < SEQ; t0 += 128) {
    float acc[4][4];
    #pragma unroll
    for (int i = 0; i < 4; ++i)
      #pragma unroll
      for (int j = 0; j < 4; ++j) acc[i][j] = 0.f;

    for (int k0 = 0; k0 < DIM; k0 += 32) {
      float4 a = *(const float4*)(qproj + (size_t)(row0 + lrow) * DIM + k0 + lk);
      sm.p1.A[lk + 0][lrow] = a.x;
      sm.p1.A[lk + 1][lrow] = a.y;
      sm.p1.A[lk + 2][lrow] = a.z;
      sm.p1.A[lk + 3][lrow] = a.w;
      #pragma unroll
      for (int it = 0; it < 2; ++it) {
        int r = lrow + it * 64;
        float4 kv = *(const float4*)(keysb + (size_t)(t0 + r) * DIM + k0 + lk);
        sm.p1.Bt[lk + 0][r] = kv.x;
        sm.p1.Bt[lk + 1][r] = kv.y;
        sm.p1.Bt[lk + 2][r] = kv.z;
        sm.p1.Bt[lk + 3][r] = kv.w;
      }
      __syncthreads();
      #pragma unroll
      for (int k = 0; k < 32; ++k) {
        float4 av = *(const float4*)&sm.p1.A[k][ty * 4];
        float4 bv = *(const float4*)&sm.p1.Bt[k][tx * 4];
        float ar[4] = {av.x, av.y, av.z, av.w};
        float br[4] = {bv.x, bv.y, bv.z, bv.w};
        #pragma unroll
        for (int i = 0; i < 4; ++i)
          #pragma unroll
          for (int j = 0; j < 4; ++j)
            acc[i][j] = fmaf(ar[i], br[j], acc[i][j]);
      }
      __syncthreads();
    }
    #pragma unroll
    for (int i = 0; i < 4; ++i) {
      size_t grow = (size_t)row0 + ty * 4 + i;
      int tcol = t0 + tx * 4;
      int4 mk = *(const int4*)(mask + grow * SEQ + tcol);
      float4 s;
      s.x = (mk.x == 0) ? NEGMASK : acc[i][0];
      s.y = (mk.y == 0) ? NEGMASK : acc[i][1];
      s.z = (mk.z == 0) ? NEGMASK : acc[i][2];
      s.w = (mk.w == 0) ? NEGMASK : acc[i][3];
      *(float4*)(scores_ws + grow * SEQ + tcol) = s;
    }
  }
  __syncthreads();   // phase-1 global writes visible block-wide; LDS reuse safe

  // ---- phase 2: per-wave row processing ----
  const int wave = tid >> 6;
  const int lane = tid & 63;
  float* rowbuf = sm.rows[wave];
  for (int rr = 0; rr < 8; ++rr) {
    const int r = wave * 8 + rr;
    const size_t grow = (size_t)row0 + r;
    const float* srow = scores_ws + grow * SEQ;
    #pragma unroll
    for (int i = 0; i < 8; ++i) {
      *(float4*)(rowbuf + lane * 4 + i * 256) = *(const float4*)(srow + lane * 4 + i * 256);
    }
    asm volatile("s_waitcnt lgkmcnt(0)" ::: "memory");

    // row max
    float mv = -3e38f;
    #pragma unroll
    for (int i = 0; i < 32; ++i) mv = fmaxf(mv, rowbuf[lane + i * 64]);
    #pragma unroll
    for (int off = 32; off > 0; off >>= 1) mv = fmaxf(mv, __shfl_xor(mv, off));
    const bool dead = (mv <= -1e29f);   // fully-masked row

    // Z = sum exp(s - m) over unmasked (masked underflow to 0)
    float Z = 1.f;
    if (!dead) {
      float zs = 0.f;
      #pragma unroll
      for (int i = 0; i < 32; ++i) zs += __expf(rowbuf[lane + i * 64] - mv);
      #pragma unroll
      for (int off = 32; off > 0; off >>= 1) zs += __shfl_xor(zs, off);
      Z = zs;
    }

    float total_g = 0.f;
    float oacc[16];
    #pragma unroll
    for (int j = 0; j < 16; ++j) oacc[j] = 0.f;

    if (!dead) {
      const float thresh = mv - 30.0f;   // alpha below exp(-30): exp(a)-1 < 1e-13, negligible
      for (int itk = 0; itk < TOPK; ++itk) {
        // argmax over remaining (ties -> lowest index, matching jax top_k)
        float bv = -3e38f; int bi = 1 << 30;
        #pragma unroll
        for (int i = 0; i < 32; ++i) {
          float v = rowbuf[lane + i * 64];
          int idx = lane + i * 64;
          if (v > bv) { bv = v; bi = idx; }
        }
        #pragma unroll
        for (int off = 32; off > 0; off >>= 1) {
          float ov = __shfl_xor(bv, off);
          int   oi = __shfl_xor(bi, off);
          if (ov > bv || (ov == bv && oi < bi)) { bv = ov; bi = oi; }
        }
        if (bv < thresh) break;
        float alpha = __expf(bv - mv) / Z;      // first-softmax probability
        float g = expm1f(alpha);                // exp(alpha) - 1
        total_g += g;
        const float* vrow = values + ((size_t)b * SEQ + bi) * DIM;
        #pragma unroll
        for (int j = 0; j < 16; ++j)
          oacc[j] = fmaf(g, vrow[lane + j * 64], oacc[j]);
        if (lane == 0) rowbuf[bi] = -3e38f;     // remove extracted
        asm volatile("s_waitcnt lgkmcnt(0)" ::: "memory");
      }
    }

    // out = (colsum + sum g*v) / (2048 + sum g)
    const float inv = 1.0f / (2048.0f + total_g);
    const float* cs = colsum + (size_t)b * DIM;
    float* orow = out + grow * DIM;
    #pragma unroll
    for (int j = 0; j < 16; ++j)
      orow[lane + j * 64] = (cs[lane + j * 64] + oacc[j]) * inv;
  }
}

extern "C" void kernel_launch(void* const* d_in, const int* in_sizes, int n_in,
                              void* d_out, int out_size, void* d_ws, size_t ws_size,
                              hipStream_t stream) {
  const float* queries = (const float*)d_in[0];
  const float* keys    = (const float*)d_in[1];
  const float* values  = (const float*)d_in[2];
  const int*   mask    = (const int*)d_in[3];
  const float* W       = (const float*)d_in[4];
  float* out = (float*)d_out;

  // ws layout (floats): qproj 16384*1024 | scores 16384*2048 | colsum 8192 | partial 65536
  float* qproj   = (float*)d_ws;
  float* scores  = qproj + (size_t)16384 * 1024;
  float* colsum  = scores + (size_t)16384 * 2048;
  float* partial = colsum + 8 * 1024;

  colsum_partial_kernel<<<256, 256, 0, stream>>>(values, partial);
  colsum_reduce_kernel<<<32, 256, 0, stream>>>(partial, colsum);
  dim3 gq(256, 16);   // 16384/64 x 1024/64
  qproj_kernel<<<gq, 256, 0, stream>>>(queries, W, qproj);
  scores_kernel<<<256, 512, 0, stream>>>(qproj, keys, values, mask, colsum, scores, out);
}

// Round 2
// 645.320 us; speedup vs baseline: 5.6871x; 5.6871x over previous
//
#include <hip/hip_runtime.h>
#include <math.h>

#define BATCH 8
#define SEQ   2048      // LQ == LK
#define DIM   1024      // DQ == DK == DV
#define TOPK  64
#define NEGMASK -1e30f

typedef _Float16 f16;
typedef _Float16 f16x8 __attribute__((ext_vector_type(8)));
typedef float f32x4 __attribute__((ext_vector_type(4)));

// async global->LDS, 16B per lane; LDS dest is wave-uniform base + lane*16.
__device__ __forceinline__ void async_load16(const void* g, void* l) {
  __builtin_amdgcn_global_load_lds(
      (const __attribute__((address_space(1))) void*)g,
      (__attribute__((address_space(3))) void*)l, 16, 0, 0);
}

// ---------------- colsum of values over t, per (b, d) ----------------
__global__ __launch_bounds__(256) void colsum_partial_kernel(
    const float* __restrict__ values, float* __restrict__ partial) {
  int bid = blockIdx.x;          // 256 = tc(8) * b(8) * dg(4)
  int tc = bid >> 5;
  int b  = (bid >> 2) & 7;
  int dg = bid & 3;
  int d  = dg * 256 + threadIdx.x;
  const float* vp = values + ((size_t)b * SEQ + (size_t)tc * 256) * DIM + d;
  float s = 0.f;
  #pragma unroll 8
  for (int t = 0; t < 256; ++t) s += vp[(size_t)t * DIM];
  partial[((size_t)tc * BATCH + b) * DIM + d] = s;
}

__global__ __launch_bounds__(256) void colsum_reduce_kernel(
    const float* __restrict__ partial, float* __restrict__ colsum) {
  int idx = blockIdx.x * 256 + threadIdx.x;   // 8192 = 8*1024
  float s = 0.f;
  #pragma unroll
  for (int tc = 0; tc < 8; ++tc) s += partial[(size_t)tc * 8192 + idx];
  colsum[idx] = s;
}

// ---------------- f32 -> f16 conversion ----------------
__global__ __launch_bounds__(256) void cvt_f32_to_f16(
    const float* __restrict__ in, f16* __restrict__ out, int n) {
  int i = (blockIdx.x * 256 + threadIdx.x) * 4;
  if (i >= n) return;
  float4 v = *(const float4*)(in + i);
  union { f16 h[4]; uint2 u; } pk;
  pk.h[0] = (f16)v.x; pk.h[1] = (f16)v.y; pk.h[2] = (f16)v.z; pk.h[3] = (f16)v.w;
  *(uint2*)(out + i) = pk.u;
}

// ---------------- MFMA bt-GEMM core (m97 structure, fp16) ----------------
// C[128][128] per block = A-panel[128][K] . B-panel[128][K]^T, BK=32.
// LDS tile layout: [128 rows][4 slots of 8 f16], slot XOR-swizzled:
// storage slot s at row r holds logical k-group s ^ ((r>>1)&3).
// Staged via global_load_lds (linear LDS dest, pre-swizzled global source);
// fragment ds_read_b128 applies the same XOR -> conflict-free (8-lane phases
// cover all 32 banks).

#define GEMM_PROLOGUE(APTR, BPTR)                                           \
  const int tid = threadIdx.x;                                              \
  const int wave = tid >> 6, lane = tid & 63;                               \
  const int wm = (wave >> 1) * 64, wn = (wave & 1) * 64;                    \
  const int r0 = wave * 32 + (lane >> 2);                                   \
  const int c16 = (lane & 3) ^ ((r0 >> 1) & 3);                            \
  const f16* srcA0 = (APTR) + (size_t)(m0 + r0) * DIM + c16 * 8;           \
  const f16* srcA1 = (APTR) + (size_t)(m0 + r0 + 16) * DIM + c16 * 8;      \
  const f16* srcB0 = (BPTR) + (size_t)(n0 + r0) * DIM + c16 * 8;           \
  const f16* srcB1 = (BPTR) + (size_t)(n0 + r0 + 16) * DIM + c16 * 8;      \
  char* ldsA0 = smA + wave * 2048;                                          \
  char* ldsA1 = smA + wave * 2048 + 1024;                                   \
  char* ldsB0 = smB + wave * 2048;                                          \
  char* ldsB1 = smB + wave * 2048 + 1024;                                   \
  int offA[4], offB[4];                                                     \
  _Pragma("unroll")                                                         \
  for (int i = 0; i < 4; ++i) {                                             \
    int r = wm + i * 16 + (lane & 15);                                      \
    offA[i] = r * 64 + ((lane >> 4) ^ ((r >> 1) & 3)) * 16;                 \
    int rn = wn + i * 16 + (lane & 15);                                     \
    offB[i] = rn * 64 + ((lane >> 4) ^ ((rn >> 1) & 3)) * 16;               \
  }                                                                         \
  f32x4 acc[4][4];                                                          \
  _Pragma("unroll")                                                         \
  for (int i = 0; i < 4; ++i)                                               \
    _Pragma("unroll")                                                       \
    for (int j = 0; j < 4; ++j)                                             \
      acc[i][j] = (f32x4){0.f, 0.f, 0.f, 0.f};                              \
  for (int k0 = 0; k0 < DIM; k0 += 32) {                                    \
    async_load16(srcA0 + k0, ldsA0);                                        \
    async_load16(srcA1 + k0, ldsA1);                                        \
    async_load16(srcB0 + k0, ldsB0);                                        \
    async_load16(srcB1 + k0, ldsB1);                                        \
    __syncthreads();                                                        \
    f16x8 af[4], bf[4];                                                     \
    _Pragma("unroll")                                                       \
    for (int i = 0; i < 4; ++i) {                                           \
      af[i] = *(const f16x8*)(smA + offA[i]);                               \
      bf[i] = *(const f16x8*)(smB + offB[i]);                               \
    }                                                                       \
    _Pragma("unroll")                                                       \
    for (int i = 0; i < 4; ++i)                                             \
      _Pragma("unroll")                                                     \
      for (int j = 0; j < 4; ++j)                                           \
        acc[i][j] = __builtin_amdgcn_mfma_f32_16x16x32_f16(                 \
            af[i], bf[j], acc[i][j], 0, 0, 0);                              \
    __syncthreads();                                                        \
  }

__global__ __launch_bounds__(256) void gemm_qproj(
    const f16* __restrict__ A, const f16* __restrict__ Bw,
    f16* __restrict__ C) {
  __shared__ __align__(128) char smA[8192];
  __shared__ __align__(128) char smB[8192];
  const int m0 = blockIdx.y * 128;
  const int n0 = blockIdx.x * 128;
  GEMM_PROLOGUE(A, Bw)
  // C/D layout (verified m89/m91): col = lane&15, row = (lane>>4)*4 + reg
  const int cr = m0 + wm + (lane >> 4) * 4;
  const int cc = n0 + wn + (lane & 15);
  #pragma unroll
  for (int i = 0; i < 4; ++i)
    #pragma unroll
    for (int j = 0; j < 4; ++j)
      #pragma unroll
      for (int reg = 0; reg < 4; ++reg)
        C[(size_t)(cr + i * 16 + reg) * DIM + cc + j * 16] = (f16)acc[i][j][reg];
}

__global__ __launch_bounds__(256) void gemm_scores(
    const f16* __restrict__ QP, const f16* __restrict__ K16,
    const int* __restrict__ mask, float* __restrict__ S) {
  __shared__ __align__(128) char smA[8192];
  __shared__ __align__(128) char smB[8192];
  const int m0 = blockIdx.y * 128;     // global flat q-row (b*2048 + q)
  const int n0 = blockIdx.x * 128;     // t col within batch
  const int b  = m0 >> 11;
  const f16* Bk = K16 + (size_t)b * SEQ * DIM;
  GEMM_PROLOGUE(QP, Bk)
  const int cr = m0 + wm + (lane >> 4) * 4;
  const int cc = n0 + wn + (lane & 15);
  #pragma unroll
  for (int i = 0; i < 4; ++i)
    #pragma unroll
    for (int j = 0; j < 4; ++j)
      #pragma unroll
      for (int reg = 0; reg < 4; ++reg) {
        size_t off = (size_t)(cr + i * 16 + reg) * SEQ + cc + j * 16;
        S[off] = mask[off] ? acc[i][j][reg] : NEGMASK;
      }
}

// ---------------- topk + gather epilogue ----------------
// One block: 64 q-rows, 8 waves; per wave, 8 rows: max, Z, descending
// top-64 extract (early stop at mv-30), V gather, fused epilogue.
__global__ __launch_bounds__(512) void topk_kernel(
    const float* __restrict__ scores_ws,   // [16384][2048] masked scores
    const float* __restrict__ values,      // [8][2048][1024]
    const float* __restrict__ colsum,      // [8][1024]
    float* __restrict__ out)               // [16384][1024]
{
  __shared__ float rows[8][2048];
  const int blk  = blockIdx.x;       // 0..255
  const int b    = blk >> 5;
  const int row0 = blk * 64;
  const int tid  = threadIdx.x;
  const int wave = tid >> 6;
  const int lane = tid & 63;
  float* rowbuf = rows[wave];

  for (int rr = 0; rr < 8; ++rr) {
    const int r = wave * 8 + rr;
    const size_t grow = (size_t)row0 + r;
    const float* srow = scores_ws + grow * SEQ;
    #pragma unroll
    for (int i = 0; i < 8; ++i)
      *(float4*)(rowbuf + lane * 4 + i * 256) = *(const float4*)(srow + lane * 4 + i * 256);
    asm volatile("s_waitcnt lgkmcnt(0)" ::: "memory");

    // row max
    float mv = -3e38f;
    #pragma unroll
    for (int i = 0; i < 32; ++i) mv = fmaxf(mv, rowbuf[lane + i * 64]);
    #pragma unroll
    for (int off = 32; off > 0; off >>= 1) mv = fmaxf(mv, __shfl_xor(mv, off));
    const bool dead = (mv <= -1e29f);   // fully-masked row

    // Z = sum exp(s - m) (masked entries underflow to 0)
    float Z = 1.f;
    if (!dead) {
      float zs = 0.f;
      #pragma unroll
      for (int i = 0; i < 32; ++i) zs += __expf(rowbuf[lane + i * 64] - mv);
      #pragma unroll
      for (int off = 32; off > 0; off >>= 1) zs += __shfl_xor(zs, off);
      Z = zs;
    }

    float total_g = 0.f;
    float oacc[16];
    #pragma unroll
    for (int j = 0; j < 16; ++j) oacc[j] = 0.f;

    if (!dead) {
      const float thresh = mv - 30.0f;  // below: expm1(alpha) < 1e-13
      for (int itk = 0; itk < TOPK; ++itk) {
        float bv = -3e38f; int bi = 1 << 30;
        #pragma unroll
        for (int i = 0; i < 32; ++i) {
          float v = rowbuf[lane + i * 64];
          int idx = lane + i * 64;
          if (v > bv) { bv = v; bi = idx; }
        }
        #pragma unroll
        for (int off = 32; off > 0; off >>= 1) {
          float ov = __shfl_xor(bv, off);
          int   oi = __shfl_xor(bi, off);
          if (ov > bv || (ov == bv && oi < bi)) { bv = ov; bi = oi; }
        }
        if (bv < thresh) break;
        float alpha = __expf(bv - mv) / Z;     // first-softmax probability
        float g = expm1f(alpha);               // exp(alpha) - 1
        total_g += g;
        const float* vrow = values + ((size_t)b * SEQ + bi) * DIM;
        #pragma unroll
        for (int j = 0; j < 16; ++j)
          oacc[j] = fmaf(g, vrow[lane + j * 64], oacc[j]);
        if (lane == 0) rowbuf[bi] = -3e38f;    // remove extracted
        asm volatile("s_waitcnt lgkmcnt(0)" ::: "memory");
      }
    }

    // out = (colsum + sum g*v) / (2048 + sum g)
    const float inv = 1.0f / (2048.0f + total_g);
    const float* cs = colsum + (size_t)b * DIM;
    float* orow = out + grow * DIM;
    #pragma unroll
    for (int j = 0; j < 16; ++j)
      orow[lane + j * 64] = (cs[lane + j * 64] + oacc[j]) * inv;
  }
}

extern "C" void kernel_launch(void* const* d_in, const int* in_sizes, int n_in,
                              void* d_out, int out_size, void* d_ws, size_t ws_size,
                              hipStream_t stream) {
  const float* queries = (const float*)d_in[0];
  const float* keys    = (const float*)d_in[1];
  const float* values  = (const float*)d_in[2];
  const int*   mask    = (const int*)d_in[3];
  const float* W       = (const float*)d_in[4];
  float* out = (float*)d_out;

  // ws layout (bytes), total ~192.3 MB:
  //   [0, 128M)    scores f32 [16384][2048]
  //       q16 aliases scores+0      (32 MB, dead before scores written)
  //       w16 aliases scores+32M    ( 2 MB, dead before scores written)
  //   [128M, 160M) qp16 f16 [16384][1024]
  //   [160M, 192M) k16  f16 [8][2048][1024]
  //   [192M, ...)  colsum f32 8192 | partial f32 65536
  char* base = (char*)d_ws;
  float* scores  = (float*)base;
  f16*   q16     = (f16*)base;
  f16*   w16     = (f16*)(base + (size_t)32 * 1024 * 1024);
  f16*   qp16    = (f16*)(base + (size_t)128 * 1024 * 1024);
  f16*   k16     = (f16*)(base + (size_t)160 * 1024 * 1024);
  float* colsum  = (float*)(base + (size_t)192 * 1024 * 1024);
  float* partial = colsum + 8192;

  colsum_partial_kernel<<<256, 256, 0, stream>>>(values, partial);
  colsum_reduce_kernel<<<32, 256, 0, stream>>>(partial, colsum);
  cvt_f32_to_f16<<<16384, 256, 0, stream>>>(queries, q16, 16384 * 1024);
  cvt_f32_to_f16<<<1024, 256, 0, stream>>>(W, w16, 1024 * 1024);
  gemm_qproj<<<dim3(8, 128), 256, 0, stream>>>(q16, w16, qp16);
  cvt_f32_to_f16<<<16384, 256, 0, stream>>>(keys, k16, 16384 * 1024);
  gemm_scores<<<dim3(16, 128), 256, 0, stream>>>(qp16, k16, mask, scores);
  topk_kernel<<<256, 512, 0, stream>>>(scores, values, colsum, out);
}

// Round 3
// 321.799 us; speedup vs baseline: 11.4046x; 2.0054x over previous
//
#include <hip/hip_runtime.h>
#include <math.h>

#define BATCH 8
#define SEQ   2048      // LQ == LK
#define DIM   1024      // DQ == DK == DV
#define TOPK  64
#define NEGMASK -1e30f
#define CAND_THRESH 16.0f   // drop alpha <= e^-16: g <= 1.1e-7, invisible at 2e-3

typedef _Float16 f16;
typedef _Float16 f16x8 __attribute__((ext_vector_type(8)));
typedef float f32x4 __attribute__((ext_vector_type(4)));

// async global->LDS, 16B per lane; LDS dest is wave-uniform base + lane*16.
__device__ __forceinline__ void async_load16(const void* g, void* l) {
  __builtin_amdgcn_global_load_lds(
      (const __attribute__((address_space(1))) void*)g,
      (__attribute__((address_space(3))) void*)l, 16, 0, 0);
}

// ---------------- colsum of values over t, per (b, d) ----------------
__global__ __launch_bounds__(256) void colsum_partial_kernel(
    const float* __restrict__ values, float* __restrict__ partial) {
  int bid = blockIdx.x;          // 256 = tc(8) * b(8) * dg(4)
  int tc = bid >> 5;
  int b  = (bid >> 2) & 7;
  int dg = bid & 3;
  int d  = dg * 256 + threadIdx.x;
  const float* vp = values + ((size_t)b * SEQ + (size_t)tc * 256) * DIM + d;
  float s = 0.f;
  #pragma unroll 8
  for (int t = 0; t < 256; ++t) s += vp[(size_t)t * DIM];
  partial[((size_t)tc * BATCH + b) * DIM + d] = s;
}

__global__ __launch_bounds__(256) void colsum_reduce_kernel(
    const float* __restrict__ partial, float* __restrict__ colsum) {
  int idx = blockIdx.x * 256 + threadIdx.x;   // 8192 = 8*1024
  float s = 0.f;
  #pragma unroll
  for (int tc = 0; tc < 8; ++tc) s += partial[(size_t)tc * 8192 + idx];
  colsum[idx] = s;
}

// ---------------- f32 -> f16 conversion ----------------
__global__ __launch_bounds__(256) void cvt_f32_to_f16(
    const float* __restrict__ in, f16* __restrict__ out, int n) {
  int i = (blockIdx.x * 256 + threadIdx.x) * 4;
  if (i >= n) return;
  float4 v = *(const float4*)(in + i);
  union { f16 h[4]; uint2 u; } pk;
  pk.h[0] = (f16)v.x; pk.h[1] = (f16)v.y; pk.h[2] = (f16)v.z; pk.h[3] = (f16)v.w;
  *(uint2*)(out + i) = pk.u;
}

// ---------------- MFMA bt-GEMM core (m97 structure, fp16) ----------------
// C[128][128] per block = A-panel[128][K] . B-panel[128][K]^T, BK=32.
// LDS tile: [128 rows][4 slots of 8 f16], slot XOR-swizzled (rule #21:
// linear LDS dest via global_load_lds + inverse-swizzled global src +
// swizzled ds_read_b128) -> conflict-free fragment reads.

#define GEMM_PROLOGUE(APTR, BPTR)                                           \
  const int tid = threadIdx.x;                                              \
  const int wave = tid >> 6, lane = tid & 63;                               \
  const int wm = (wave >> 1) * 64, wn = (wave & 1) * 64;                    \
  const int r0 = wave * 32 + (lane >> 2);                                   \
  const int c16 = (lane & 3) ^ ((r0 >> 1) & 3);                            \
  const f16* srcA0 = (APTR) + (size_t)(m0 + r0) * DIM + c16 * 8;           \
  const f16* srcA1 = (APTR) + (size_t)(m0 + r0 + 16) * DIM + c16 * 8;      \
  const f16* srcB0 = (BPTR) + (size_t)(n0 + r0) * DIM + c16 * 8;           \
  const f16* srcB1 = (BPTR) + (size_t)(n0 + r0 + 16) * DIM + c16 * 8;      \
  char* ldsA0 = smA + wave * 2048;                                          \
  char* ldsA1 = smA + wave * 2048 + 1024;                                   \
  char* ldsB0 = smB + wave * 2048;                                          \
  char* ldsB1 = smB + wave * 2048 + 1024;                                   \
  int offA[4], offB[4];                                                     \
  _Pragma("unroll")                                                         \
  for (int i = 0; i < 4; ++i) {                                             \
    int r = wm + i * 16 + (lane & 15);                                      \
    offA[i] = r * 64 + ((lane >> 4) ^ ((r >> 1) & 3)) * 16;                 \
    int rn = wn + i * 16 + (lane & 15);                                     \
    offB[i] = rn * 64 + ((lane >> 4) ^ ((rn >> 1) & 3)) * 16;               \
  }                                                                         \
  f32x4 acc[4][4];                                                          \
  _Pragma("unroll")                                                         \
  for (int i = 0; i < 4; ++i)                                               \
    _Pragma("unroll")                                                       \
    for (int j = 0; j < 4; ++j)                                             \
      acc[i][j] = (f32x4){0.f, 0.f, 0.f, 0.f};                              \
  for (int k0 = 0; k0 < DIM; k0 += 32) {                                    \
    async_load16(srcA0 + k0, ldsA0);                                        \
    async_load16(srcA1 + k0, ldsA1);                                        \
    async_load16(srcB0 + k0, ldsB0);                                        \
    async_load16(srcB1 + k0, ldsB1);                                        \
    __syncthreads();                                                        \
    f16x8 af[4], bf[4];                                                     \
    _Pragma("unroll")                                                       \
    for (int i = 0; i < 4; ++i) {                                           \
      af[i] = *(const f16x8*)(smA + offA[i]);                               \
      bf[i] = *(const f16x8*)(smB + offB[i]);                               \
    }                                                                       \
    _Pragma("unroll")                                                       \
    for (int i = 0; i < 4; ++i)                                             \
      _Pragma("unroll")                                                     \
      for (int j = 0; j < 4; ++j)                                           \
        acc[i][j] = __builtin_amdgcn_mfma_f32_16x16x32_f16(                 \
            af[i], bf[j], acc[i][j], 0, 0, 0);                              \
    __syncthreads();                                                        \
  }

__global__ __launch_bounds__(256) void gemm_qproj(
    const f16* __restrict__ A, const f16* __restrict__ Bw,
    f16* __restrict__ C) {
  __shared__ __align__(128) char smA[8192];
  __shared__ __align__(128) char smB[8192];
  const int m0 = blockIdx.y * 128;
  const int n0 = blockIdx.x * 128;
  GEMM_PROLOGUE(A, Bw)
  // C/D layout (verified m89/m91): col = lane&15, row = (lane>>4)*4 + reg
  const int cr = m0 + wm + (lane >> 4) * 4;
  const int cc = n0 + wn + (lane & 15);
  #pragma unroll
  for (int i = 0; i < 4; ++i)
    #pragma unroll
    for (int j = 0; j < 4; ++j)
      #pragma unroll
      for (int reg = 0; reg < 4; ++reg)
        C[(size_t)(cr + i * 16 + reg) * DIM + cc + j * 16] = (f16)acc[i][j][reg];
}

__global__ __launch_bounds__(256) void gemm_scores(
    const f16* __restrict__ QP, const f16* __restrict__ K16,
    const int* __restrict__ mask, float* __restrict__ S) {
  __shared__ __align__(128) char smA[8192];
  __shared__ __align__(128) char smB[8192];
  const int m0 = blockIdx.y * 128;     // global flat q-row (b*2048 + q)
  const int n0 = blockIdx.x * 128;     // t col within batch
  const int b  = m0 >> 11;
  const f16* Bk = K16 + (size_t)b * SEQ * DIM;
  GEMM_PROLOGUE(QP, Bk)
  const int cr = m0 + wm + (lane >> 4) * 4;
  const int cc = n0 + wn + (lane & 15);
  #pragma unroll
  for (int i = 0; i < 4; ++i)
    #pragma unroll
    for (int j = 0; j < 4; ++j)
      #pragma unroll
      for (int reg = 0; reg < 4; ++reg) {
        size_t off = (size_t)(cr + i * 16 + reg) * SEQ + cc + j * 16;
        S[off] = mask[off] ? acc[i][j][reg] : NEGMASK;
      }
}

// ---------------- topk epilogue: ballot compaction, no serial extract ----------------
// 1 wave per q-row. Row streamed once into 32 VGPRs (scores are LLC-hot).
// max -> Z -> ballot-compact candidates {s > mv-16} (exp ~4/row) -> gather V.
// If count <= 64 the candidate set IS the significant top-k (rest have
// g <= 1.1e-7). Rare count>64 path: serial extract over the compact list.
__global__ __launch_bounds__(512) void topk_kernel(
    const float* __restrict__ scores_ws,   // [16384][2048] masked scores
    const float* __restrict__ values,      // [8][2048][1024]
    const float* __restrict__ colsum,      // [8][1024]
    float* __restrict__ out)               // [16384][1024]
{
  __shared__ int   cidx[8][128];
  __shared__ float csc[8][128];
  const int wave = threadIdx.x >> 6;
  const int lane = threadIdx.x & 63;
  const int grow = blockIdx.x * 8 + wave;      // global flat q-row
  const int b    = grow >> 11;
  const float* srow = scores_ws + (size_t)grow * SEQ;
  int*   myidx = cidx[wave];
  float* mysc  = csc[wave];

  // stream row into registers: s4[i] = row[i*256 + lane*4 .. +3]
  f32x4 s4[8];
  #pragma unroll
  for (int i = 0; i < 8; ++i)
    s4[i] = *(const f32x4*)(srow + i * 256 + lane * 4);

  // row max
  float mv = -3e38f;
  #pragma unroll
  for (int i = 0; i < 8; ++i)
    #pragma unroll
    for (int j = 0; j < 4; ++j) mv = fmaxf(mv, s4[i][j]);
  #pragma unroll
  for (int off = 32; off > 0; off >>= 1) mv = fmaxf(mv, __shfl_xor(mv, off));
  const bool dead = (mv <= -1e29f);   // fully-masked row -> uniform softmax

  // Z = sum exp(s - mv) (masked entries: exp(-huge) -> 0)
  float Z = 1.f;
  if (!dead) {
    float zs = 0.f;
    #pragma unroll
    for (int i = 0; i < 8; ++i)
      #pragma unroll
      for (int j = 0; j < 4; ++j) zs += __expf(s4[i][j] - mv);
    #pragma unroll
    for (int off = 32; off > 0; off >>= 1) zs += __shfl_xor(zs, off);
    Z = zs;
  }
  const float invZ = 1.0f / Z;

  // ballot compaction of candidates (deterministic (i,j,lane) order)
  int cnt = 0;
  if (!dead) {
    const float thresh = mv - CAND_THRESH;
    const unsigned long long lmlt = (1ull << lane) - 1ull;
    #pragma unroll
    for (int i = 0; i < 8; ++i)
      #pragma unroll
      for (int j = 0; j < 4; ++j) {
        bool c = s4[i][j] > thresh;
        unsigned long long m = __ballot(c);
        if (c) {
          int pos = cnt + __popcll(m & lmlt);
          if (pos < 128) { myidx[pos] = i * 256 + lane * 4 + j; mysc[pos] = s4[i][j]; }
        }
        cnt += __popcll(m);
      }
  }
  asm volatile("s_waitcnt lgkmcnt(0)" ::: "memory");

  float total_g = 0.f;
  f32x4 oacc[4];
  #pragma unroll
  for (int j = 0; j < 4; ++j) oacc[j] = (f32x4){0.f, 0.f, 0.f, 0.f};
  const float* vbase = values + (size_t)b * SEQ * DIM;

  if (cnt <= 64) {
    // common path: every candidate is a significant top-k member
    for (int c = 0; c < cnt; ++c) {
      float g = expm1f(__expf(mysc[c] - mv) * invZ);
      total_g += g;
      const float* vrow = vbase + (size_t)myidx[c] * DIM;
      #pragma unroll
      for (int j = 0; j < 4; ++j) {
        f32x4 v = *(const f32x4*)(vrow + j * 256 + lane * 4);
        #pragma unroll
        for (int e = 0; e < 4; ++e) oacc[j][e] = fmaf(g, v[e], oacc[j][e]);
      }
    }
  } else {
    // rare path (never expected on this data): top-64 by (score desc, idx asc)
    int nlist = cnt < 128 ? cnt : 128;
    for (int itk = 0; itk < TOPK; ++itk) {
      float bv = -3e38f; int bi = 1 << 30; int bsl = -1;
      #pragma unroll
      for (int h = 0; h < 2; ++h) {
        int sl = lane + h * 64;
        if (sl < nlist) {
          float v = mysc[sl]; int id = myidx[sl];
          if (v > bv || (v == bv && id < bi)) { bv = v; bi = id; bsl = sl; }
        }
      }
      #pragma unroll
      for (int off = 32; off > 0; off >>= 1) {
        float ov = __shfl_xor(bv, off);
        int   oi = __shfl_xor(bi, off);
        int   os = __shfl_xor(bsl, off);
        if (ov > bv || (ov == bv && oi < bi)) { bv = ov; bi = oi; bsl = os; }
      }
      if (bv <= -1e29f) break;
      float g = expm1f(__expf(bv - mv) * invZ);
      total_g += g;
      const float* vrow = vbase + (size_t)bi * DIM;
      #pragma unroll
      for (int j = 0; j < 4; ++j) {
        f32x4 v = *(const f32x4*)(vrow + j * 256 + lane * 4);
        #pragma unroll
        for (int e = 0; e < 4; ++e) oacc[j][e] = fmaf(g, v[e], oacc[j][e]);
      }
      if (lane == 0) mysc[bsl] = -3e38f;
      asm volatile("s_waitcnt lgkmcnt(0)" ::: "memory");
    }
  }

  // out = (colsum + sum g*v) / (2048 + sum g)
  const float inv = 1.0f / (2048.0f + total_g);
  const float* cs = colsum + (size_t)b * DIM;
  float* orow = out + (size_t)grow * DIM;
  #pragma unroll
  for (int j = 0; j < 4; ++j) {
    f32x4 c = *(const f32x4*)(cs + j * 256 + lane * 4);
    f32x4 o;
    #pragma unroll
    for (int e = 0; e < 4; ++e) o[e] = (c[e] + oacc[j][e]) * inv;
    *(f32x4*)(orow + j * 256 + lane * 4) = o;
  }
}

extern "C" void kernel_launch(void* const* d_in, const int* in_sizes, int n_in,
                              void* d_out, int out_size, void* d_ws, size_t ws_size,
                              hipStream_t stream) {
  const float* queries = (const float*)d_in[0];
  const float* keys    = (const float*)d_in[1];
  const float* values  = (const float*)d_in[2];
  const int*   mask    = (const int*)d_in[3];
  const float* W       = (const float*)d_in[4];
  float* out = (float*)d_out;

  // ws layout (bytes), total ~192.3 MB:
  //   [0, 128M)    scores f32 [16384][2048]
  //       q16 aliases scores+0      (32 MB, dead before scores written)
  //       w16 aliases scores+32M    ( 2 MB, dead before scores written)
  //   [128M, 160M) qp16 f16 [16384][1024]
  //   [160M, 192M) k16  f16 [8][2048][1024]
  //   [192M, ...)  colsum f32 8192 | partial f32 65536
  char* base = (char*)d_ws;
  float* scores  = (float*)base;
  f16*   q16     = (f16*)base;
  f16*   w16     = (f16*)(base + (size_t)32 * 1024 * 1024);
  f16*   qp16    = (f16*)(base + (size_t)128 * 1024 * 1024);
  f16*   k16     = (f16*)(base + (size_t)160 * 1024 * 1024);
  float* colsum  = (float*)(base + (size_t)192 * 1024 * 1024);
  float* partial = colsum + 8192;

  colsum_partial_kernel<<<256, 256, 0, stream>>>(values, partial);
  colsum_reduce_kernel<<<32, 256, 0, stream>>>(partial, colsum);
  cvt_f32_to_f16<<<16384, 256, 0, stream>>>(queries, q16, 16384 * 1024);
  cvt_f32_to_f16<<<1024, 256, 0, stream>>>(W, w16, 1024 * 1024);
  gemm_qproj<<<dim3(8, 128), 256, 0, stream>>>(q16, w16, qp16);
  cvt_f32_to_f16<<<16384, 256, 0, stream>>>(keys, k16, 16384 * 1024);
  gemm_scores<<<dim3(16, 128), 256, 0, stream>>>(qp16, k16, mask, scores);
  topk_kernel<<<2048, 512, 0, stream>>>(scores, values, colsum, out);
}